// Round 1
// baseline (566.052 us; speedup 1.0000x reference)
//
#include <hip/hip_runtime.h>
#include <cstdint>

// B=4096, T=512, I=3, H=32, C=3
#define B_TOT 4096
#define T_LEN 512
#define I_DIM 3
#define H_DIM 32
#define C_DIM 3
#define WAVES_PER_BLOCK 4

__device__ __forceinline__ float sigm(float v) {
    // 1/(1+exp(-v)); v_exp + v_rcp, ~1ulp each — fine vs 1e-2 threshold.
    return __builtin_amdgcn_rcpf(1.0f + __expf(-v));
}

__global__ __launch_bounds__(256, 4)
void lstm_fused(const float* __restrict__ x,
                const float* __restrict__ W_ih,
                const float* __restrict__ W_hh,
                const float* __restrict__ b_ih,
                const float* __restrict__ b_hh,
                const float* __restrict__ W_fc,
                const float* __restrict__ b_fc,
                float* __restrict__ out)
{
    // x staging: 4 batch elems x 512 t x 3 = 6144 floats = 24 KB
    __shared__ float s_x[WAVES_PER_BLOCK * T_LEN * I_DIM];

    const int tid  = threadIdx.x;
    const int wave = tid >> 6;
    const int lane = tid & 63;
    const int b    = blockIdx.x * WAVES_PER_BLOCK + wave;

    // ---- stage x for this block's 4 consecutive batch elements (coalesced) ----
    {
        const float4* g4 = (const float4*)(x + (size_t)blockIdx.x * (WAVES_PER_BLOCK * T_LEN * I_DIM));
        float4* s4 = (float4*)s_x;
        #pragma unroll
        for (int i = 0; i < 6; ++i) s4[tid + i * 256] = g4[tid + i * 256];
    }
    __syncthreads();

    // lane l owns gate rows: rowA = l (i for l<32, f for l>=32),
    //                        rowB = l+64 (g for l<32, o for l>=32)
    const int rowA = lane;
    const int rowB = lane + 64;

    // recurrent weights in VGPRs: 64 floats/lane
    float wA[H_DIM], wB[H_DIM];
    {
        const float4* a4 = (const float4*)(W_hh + rowA * H_DIM);
        const float4* c4 = (const float4*)(W_hh + rowB * H_DIM);
        #pragma unroll
        for (int q = 0; q < 8; ++q) {
            float4 va = a4[q], vb = c4[q];
            wA[4*q+0] = va.x; wA[4*q+1] = va.y; wA[4*q+2] = va.z; wA[4*q+3] = va.w;
            wB[4*q+0] = vb.x; wB[4*q+1] = vb.y; wB[4*q+2] = vb.z; wB[4*q+3] = vb.w;
        }
    }
    const float wiA0 = W_ih[rowA*I_DIM+0], wiA1 = W_ih[rowA*I_DIM+1], wiA2 = W_ih[rowA*I_DIM+2];
    const float wiB0 = W_ih[rowB*I_DIM+0], wiB1 = W_ih[rowB*I_DIM+1], wiB2 = W_ih[rowB*I_DIM+2];
    const float bA = b_ih[rowA] + b_hh[rowA];
    const float bB = b_ih[rowB] + b_hh[rowB];

    float h = 0.0f, c = 0.0f;
    const bool lo = (lane < 32);
    const float* xs = s_x + wave * (T_LEN * I_DIM);

    for (int t = 0; t < T_LEN; ++t) {
        // broadcast LDS reads (all 64 lanes same addr -> free)
        const float x0 = xs[t*3+0], x1 = xs[t*3+1], x2 = xs[t*3+2];
        float accA = fmaf(wiA0, x0, fmaf(wiA1, x1, fmaf(wiA2, x2, bA)));
        float accB = fmaf(wiB0, x0, fmaf(wiB1, x1, fmaf(wiB2, x2, bB)));

        // recurrent matvec: h[k] broadcast via readlane (SGPR operand in FMA)
        #pragma unroll
        for (int k = 0; k < H_DIM; ++k) {
            const float hk = __int_as_float(__builtin_amdgcn_readlane(__float_as_int(h), k));
            accA = fmaf(wA[k], hk, accA);
            accB = fmaf(wB[k], hk, accB);
        }

        // rows 0..63 (accA) are i/f: sigmoid for every lane.
        const float sA = sigm(accA);
        // rows 64..127 (accB): g=tanh for lo half, o=sigmoid for hi half.
        // tanh(x) = 2*sigmoid(2x)-1, branch-free:
        const float xb = lo ? (accB + accB) : accB;
        const float tb = sigm(xb);
        const float sB = lo ? fmaf(2.0f, tb, -1.0f) : tb;

        // swap halves so every lane has (i,f,g,o) for hidden index (lane&31)
        const float sAo = __shfl_xor(sA, 32, 64);
        const float sBo = __shfl_xor(sB, 32, 64);
        const float iv = lo ? sA  : sAo;
        const float fv = lo ? sAo : sA;
        const float gv = lo ? sB  : sBo;
        const float ov = lo ? sBo : sB;

        c = fmaf(fv, c, iv * gv);
        const float tc = fmaf(2.0f, sigm(c + c), -1.0f);   // tanh(c)
        h = ov * tc;
    }

    // ---- epilogue: out[b, cc] = b_fc[cc] + sum_k W_fc[cc,k] * h[k] ----
    {
        const int r = (lane < C_DIM) ? lane : 0;
        const float* wf = W_fc + r * H_DIM;
        float acc = b_fc[r];
        #pragma unroll
        for (int k = 0; k < H_DIM; ++k) {
            const float hk = __int_as_float(__builtin_amdgcn_readlane(__float_as_int(h), k));
            acc = fmaf(wf[k], hk, acc);
        }
        if (lane < C_DIM) out[b * C_DIM + lane] = acc;
    }
}

extern "C" void kernel_launch(void* const* d_in, const int* in_sizes, int n_in,
                              void* d_out, int out_size, void* d_ws, size_t ws_size,
                              hipStream_t stream) {
    const float* x    = (const float*)d_in[0];
    const float* W_ih = (const float*)d_in[1];
    const float* W_hh = (const float*)d_in[2];
    const float* b_ih = (const float*)d_in[3];
    const float* b_hh = (const float*)d_in[4];
    const float* W_fc = (const float*)d_in[5];
    const float* b_fc = (const float*)d_in[6];
    float* out = (float*)d_out;

    dim3 grid(B_TOT / WAVES_PER_BLOCK);   // 1024 blocks
    dim3 block(64 * WAVES_PER_BLOCK);     // 256 threads = 4 waves
    lstm_fused<<<grid, block, 0, stream>>>(x, W_ih, W_hh, b_ih, b_hh, W_fc, b_fc, out);
}

// Round 2
// 323.248 us; speedup vs baseline: 1.7511x; 1.7511x over previous
//
#include <hip/hip_runtime.h>
#include <cstdint>

// B=4096, T=512, I=3, H=32, C=3
#define B_TOT 4096
#define T_LEN 512
#define CHUNK 128

typedef _Float16 f16x8 __attribute__((ext_vector_type(8)));
typedef _Float16 f16x4 __attribute__((ext_vector_type(4)));
typedef float    f32x4 __attribute__((ext_vector_type(4)));

__device__ __forceinline__ float sigm(float v) {
    return __builtin_amdgcn_rcpf(1.0f + __expf(-v));
}

// One block = 16 batches, 4 waves. Wave w owns hidden slice [8w, 8w+8).
// Per step, wave w computes its 32 gate columns via 2 MFMAs:
//   mfma0 columns: n<8 -> i-gate, n>=8 -> f-gate   (hid = 8w + (n&7))
//   mfma1 columns: n<8 -> g-gate, n>=8 -> o-gate
// Input term W_ih*x_t + (b_ih+b_hh) folded in via a padded x-MFMA + acc init.
__global__ __launch_bounds__(256, 1)
void lstm_mfma(const float* __restrict__ x,
               const float* __restrict__ W_ih,
               const float* __restrict__ W_hh,
               const float* __restrict__ b_ih,
               const float* __restrict__ b_hh,
               const float* __restrict__ W_fc,
               const float* __restrict__ b_fc,
               float* __restrict__ out)
{
    __shared__ _Float16 hbuf[2][16][32];       // [buf][batch][hid], 2 KB
    __shared__ _Float16 xbuf[CHUNK][16][4];    // [t_local][batch][i(pad4)], 16 KB

    const int tid  = threadIdx.x;
    const int wave = tid >> 6;        // 0..3 -> hid slice 8*wave
    const int lane = tid & 63;
    const int n    = lane & 15;       // mfma column
    const int kq   = lane >> 4;       // k-quad (A/B fragment k = 8*kq+j)
    const bool lo8 = (n < 8);
    const int hid  = 8 * wave + (n & 7);
    const int tb   = blockIdx.x * 16; // batch tile base

    // W rows for this lane's two columns (PyTorch gate order i,f,g,o)
    const int R0 = (lo8 ? 0 : 32) + hid;   // i or f
    const int R1 = (lo8 ? 64 : 96) + hid;  // g or o

    // ---- loop-invariant B fragments (fp16, in VGPRs) ----
    f16x8 b0, b1;
#pragma unroll
    for (int j = 0; j < 8; ++j) {
        b0[j] = (_Float16)W_hh[R0 * 32 + 8 * kq + j];
        b1[j] = (_Float16)W_hh[R1 * 32 + 8 * kq + j];
    }
    f16x8 b2_0 = {}, b2_1 = {};   // W_ih padded to K=32 (k<3 nonzero)
    if (kq == 0) {
#pragma unroll
        for (int j = 0; j < 3; ++j) {
            b2_0[j] = (_Float16)W_ih[R0 * 3 + j];
            b2_1[j] = (_Float16)W_ih[R1 * 3 + j];
        }
    }
    const float bias0 = b_ih[R0] + b_hh[R0];
    const float bias1 = b_ih[R1] + b_hh[R1];

    // zero h(0) buffer: 16*32 halves = 256 ints
    ((int*)&hbuf[0][0][0])[tid] = 0;

    // c state for my two batches (same hid): batches 4*kq + (lo8?0:2) and +1
    float cA = 0.0f, cB = 0.0f;
    const int mA = 4 * kq + (lo8 ? 0 : 2);

    for (int tc = 0; tc < T_LEN; tc += CHUNK) {
        // ---- stage x chunk as fp16 [t][m][4] with zero pad ----
#pragma unroll
        for (int s = 0; s < (CHUNK * 16) / 256; ++s) {
            const int idx = tid + s * 256;
            const int tl = idx >> 4, m = idx & 15;
            const float* xp = x + ((size_t)(tb + m) * T_LEN + (tc + tl)) * 3;
            xbuf[tl][m][0] = (_Float16)xp[0];
            xbuf[tl][m][1] = (_Float16)xp[1];
            xbuf[tl][m][2] = (_Float16)xp[2];
            xbuf[tl][m][3] = (_Float16)0.0f;
        }
        __syncthreads();

        for (int tt = 0; tt < CHUNK; ++tt) {
            const int p = (tc + tt) & 1;

            // A fragment: h(t)  (A[m=n][k=8kq+j])
            const f16x8 ah = *(const f16x8*)&hbuf[p][n][8 * kq];

            // A2 fragment: x_t padded (only kq==0 lanes carry data)
            f16x8 a2 = {};
            if (kq == 0) {
                const f16x4 xv = *(const f16x4*)&xbuf[tt][n][0];
                a2[0] = xv[0]; a2[1] = xv[1]; a2[2] = xv[2];
            }

            f32x4 acc0 = {bias0, bias0, bias0, bias0};
            f32x4 acc1 = {bias1, bias1, bias1, bias1};
            acc0 = __builtin_amdgcn_mfma_f32_16x16x32_f16(a2, b2_0, acc0, 0, 0, 0);
            acc1 = __builtin_amdgcn_mfma_f32_16x16x32_f16(a2, b2_1, acc1, 0, 0, 0);
            acc0 = __builtin_amdgcn_mfma_f32_16x16x32_f16(ah, b0, acc0, 0, 0, 0);
            acc1 = __builtin_amdgcn_mfma_f32_16x16x32_f16(ah, b1, acc1, 0, 0, 0);

            // ---- activations: acc0 = sigmoid (i|f); acc1 = tanh(g) | sigmoid(o)
            float sA[4], sB[4];
#pragma unroll
            for (int r = 0; r < 4; ++r) {
                sA[r] = sigm(acc0[r]);
                const float v = acc1[r];
                const float s = sigm(lo8 ? (v + v) : v);
                sB[r] = lo8 ? fmaf(2.0f, s, -1.0f) : s;
            }

            // ---- exchange with lane^8 (partner has the other gate pair, same hid)
            float oA[4], oB[4];
#pragma unroll
            for (int r = 0; r < 4; ++r) {
                oA[r] = __int_as_float(__builtin_amdgcn_ds_swizzle(__float_as_int(sA[r]), 0x201F));
                oB[r] = __int_as_float(__builtin_amdgcn_ds_swizzle(__float_as_int(sB[r]), 0x201F));
            }

            // my two batches: r = {0,1} for lo8 lanes, {2,3} for hi lanes
            const float iv0 = lo8 ? sA[0] : oA[2];
            const float fv0 = lo8 ? oA[0] : sA[2];
            const float gv0 = lo8 ? sB[0] : oB[2];
            const float ov0 = lo8 ? oB[0] : sB[2];
            const float iv1 = lo8 ? sA[1] : oA[3];
            const float fv1 = lo8 ? oA[1] : sA[3];
            const float gv1 = lo8 ? sB[1] : oB[3];
            const float ov1 = lo8 ? oB[1] : sB[3];

            cA = fmaf(fv0, cA, iv0 * gv0);
            cB = fmaf(fv1, cB, iv1 * gv1);
            const float thA = fmaf(2.0f, sigm(cA + cA), -1.0f);  // tanh(cA)
            const float thB = fmaf(2.0f, sigm(cB + cB), -1.0f);
            const float h0 = ov0 * thA;
            const float h1 = ov1 * thB;

            hbuf[p ^ 1][mA][hid]     = (_Float16)h0;
            hbuf[p ^ 1][mA + 1][hid] = (_Float16)h1;
            __syncthreads();
        }
    }

    // ---- epilogue: out[tb+m][cc] = b_fc[cc] + sum_k W_fc[cc][k]*h[m][k]
    // final h is in hbuf[0] (T_LEN even); last loop barrier ordered it.
    if (tid < 48) {
        const int m = tid / 3, cc = tid % 3;
        float acc = b_fc[cc];
#pragma unroll
        for (int k = 0; k < 32; ++k)
            acc = fmaf(W_fc[cc * 32 + k], (float)hbuf[0][m][k], acc);
        out[(tb + m) * 3 + cc] = acc;
    }
}

extern "C" void kernel_launch(void* const* d_in, const int* in_sizes, int n_in,
                              void* d_out, int out_size, void* d_ws, size_t ws_size,
                              hipStream_t stream) {
    const float* x    = (const float*)d_in[0];
    const float* W_ih = (const float*)d_in[1];
    const float* W_hh = (const float*)d_in[2];
    const float* b_ih = (const float*)d_in[3];
    const float* b_hh = (const float*)d_in[4];
    const float* W_fc = (const float*)d_in[5];
    const float* b_fc = (const float*)d_in[6];
    float* out = (float*)d_out;

    dim3 grid(B_TOT / 16);   // 256 blocks, one 16-batch tile each
    dim3 block(256);         // 4 waves
    lstm_mfma<<<grid, block, 0, stream>>>(x, W_ih, W_hh, b_ih, b_hh, W_fc, b_fc, out);
}

// Round 3
// 209.747 us; speedup vs baseline: 2.6987x; 1.5411x over previous
//
#include <hip/hip_runtime.h>
#include <cstdint>

// B=4096, T=512, I=3, H=32, C=3
#define B_TOT 4096
#define T_LEN 512
#define CHUNK 128
#define LOG2E 1.44269504088896340736f

typedef _Float16 f16x8 __attribute__((ext_vector_type(8)));
typedef _Float16 f16x4 __attribute__((ext_vector_type(4)));
typedef float    f32x4 __attribute__((ext_vector_type(4)));

__device__ __forceinline__ float ex2(float v) { return __builtin_amdgcn_exp2f(v); }
__device__ __forceinline__ float rcpf_(float v) { return __builtin_amdgcn_rcpf(v); }

// Orientation: D[gate][batch] = W * h.  A = W rows (gates), B = h (batch = lane&15).
// Row permutation per wave w (tile row q = 4*kq + r):
//   accA: r=0 -> i[hid0], r=1 -> i[hid1], r=2 -> f[hid0], r=3 -> f[hid1]
//   accB: r=0 -> g[hid0], r=1 -> g[hid1], r=2 -> o[hid0], r=3 -> o[hid1]
//   hid0 = 8w + 2*kq, hid1 = hid0+1.
// => every lane owns complete (i,f,g,o) for its 2 (batch,hid) states. No exchange.
// exp scale folded into weights: sigmoid rows * -log2e, tanh(g) rows * -2log2e.
__global__ __launch_bounds__(256, 1)
void lstm_perm(const float* __restrict__ x,
               const float* __restrict__ W_ih,
               const float* __restrict__ W_hh,
               const float* __restrict__ b_ih,
               const float* __restrict__ b_hh,
               const float* __restrict__ W_fc,
               const float* __restrict__ b_fc,
               float* __restrict__ out)
{
    // stride 40 halves (80 B): keeps B-frag ds_read_b128 16B-aligned, spreads banks
    __shared__ __align__(16) _Float16 hbuf[2][16][40];   // 2.5 KB
    __shared__ __align__(16) _Float16 xbuf[CHUNK][16][4]; // 16 KB

    const int tid  = threadIdx.x;
    const int wave = tid >> 6;
    const int lane = tid & 63;
    const int n    = lane & 15;   // A-row q / B batch col / D batch col
    const int kq   = lane >> 4;
    const int tb   = blockIdx.x * 16;

    // ---- A-fragment rows (q = n): W row index + fold scale ----
    const int hid_n = 8 * wave + 2 * (n >> 2) + (n & 1);
    const int gA_n  = ((n & 3) >> 1) * 32 + hid_n;        // i (r<2) or f
    const int gB_n  = 64 + ((n & 3) >> 1) * 32 + hid_n;   // g (r<2) or o
    const float sA_n = -LOG2E;                            // i,f: sigmoid
    const float sB_n = ((n & 3) >> 1) ? -LOG2E : -2.0f * LOG2E; // o : g(tanh)

    f16x8 aA, aB;
#pragma unroll
    for (int j = 0; j < 8; ++j) {
        aA[j] = (_Float16)(sA_n * W_hh[gA_n * 32 + 8 * kq + j]);
        aB[j] = (_Float16)(sB_n * W_hh[gB_n * 32 + 8 * kq + j]);
    }
    f16x8 a2A = {}, a2B = {};   // W_ih, K-padded (k<3 on kq==0 lanes)
    if (kq == 0) {
#pragma unroll
        for (int j = 0; j < 3; ++j) {
            a2A[j] = (_Float16)(sA_n * W_ih[gA_n * 3 + j]);
            a2B[j] = (_Float16)(sB_n * W_ih[gB_n * 3 + j]);
        }
    }
    // ---- biases for D rows (q = 4*kq + r) ----
    float biasA[4], biasB[4];
#pragma unroll
    for (int r = 0; r < 4; ++r) {
        const int hid = 8 * wave + 2 * kq + (r & 1);
        const int gA  = (r >> 1) * 32 + hid;
        const int gB  = 64 + (r >> 1) * 32 + hid;
        const float sB = (r >> 1) ? -LOG2E : -2.0f * LOG2E;
        biasA[r] = -LOG2E * (b_ih[gA] + b_hh[gA]);
        biasB[r] = sB * (b_ih[gB] + b_hh[gB]);
    }

    // zero h(0) buffers
    {
        int* hz = (int*)&hbuf[0][0][0];
        for (int i = tid; i < (2 * 16 * 40) / 2; i += 256) hz[i] = 0;
    }

    float c0 = 0.0f, c1 = 0.0f;
    const int hid0 = 8 * wave + 2 * kq;

    f32x4 accxA, accxB;  // prefetched x-contribution (+bias)

    for (int tc = 0; tc < T_LEN; tc += CHUNK) {
        // ---- stage x chunk as fp16 (prev chunk consumed: last step's barrier) ----
#pragma unroll
        for (int s = 0; s < 8; ++s) {
            const int idx = tid + s * 256;      // 2048 (t,m) pairs
            const int tl = idx >> 4, m = idx & 15;
            const float* xp = x + ((size_t)(tb + m) * T_LEN + (tc + tl)) * 3;
            f16x4 v;
            v[0] = (_Float16)xp[0]; v[1] = (_Float16)xp[1];
            v[2] = (_Float16)xp[2]; v[3] = (_Float16)0.0f;
            *(f16x4*)&xbuf[tl][m][0] = v;
        }
        __syncthreads();

        // x-part for first step of this chunk
        {
            const f16x4 xv = *(const f16x4*)&xbuf[0][n][0];
            f16x8 b2 = {};
            b2[0] = xv[0]; b2[1] = xv[1]; b2[2] = xv[2];
            accxA = f32x4{biasA[0], biasA[1], biasA[2], biasA[3]};
            accxB = f32x4{biasB[0], biasB[1], biasB[2], biasB[3]};
            accxA = __builtin_amdgcn_mfma_f32_16x16x32_f16(a2A, b2, accxA, 0, 0, 0);
            accxB = __builtin_amdgcn_mfma_f32_16x16x32_f16(a2B, b2, accxB, 0, 0, 0);
        }

#pragma unroll 2
        for (int tt = 0; tt < CHUNK; ++tt) {
            const int p = tt & 1;   // tc is a multiple of CHUNK (even)

            // post-barrier critical path: read h -> 2 MFMA -> activations -> write
            const f16x8 bh = *(const f16x8*)&hbuf[p][n][8 * kq];
            const f32x4 accA = __builtin_amdgcn_mfma_f32_16x16x32_f16(aA, bh, accxA, 0, 0, 0);
            const f32x4 accB = __builtin_amdgcn_mfma_f32_16x16x32_f16(aB, bh, accxB, 0, 0, 0);

            const float i0 = rcpf_(1.0f + ex2(accA[0]));
            const float i1 = rcpf_(1.0f + ex2(accA[1]));
            const float f0 = rcpf_(1.0f + ex2(accA[2]));
            const float f1 = rcpf_(1.0f + ex2(accA[3]));
            const float g0 = fmaf(2.0f, rcpf_(1.0f + ex2(accB[0])), -1.0f);
            const float g1 = fmaf(2.0f, rcpf_(1.0f + ex2(accB[1])), -1.0f);
            const float o0 = rcpf_(1.0f + ex2(accB[2]));
            const float o1 = rcpf_(1.0f + ex2(accB[3]));

            c0 = fmaf(f0, c0, i0 * g0);
            c1 = fmaf(f1, c1, i1 * g1);
            const float t0 = fmaf(2.0f, rcpf_(1.0f + ex2(c0 * (-2.0f * LOG2E))), -1.0f);
            const float t1 = fmaf(2.0f, rcpf_(1.0f + ex2(c1 * (-2.0f * LOG2E))), -1.0f);
            const float h0 = o0 * t0, h1 = o1 * t1;

            union { _Float16 h2[2]; int i32; } pk;
            pk.h2[0] = (_Float16)h0; pk.h2[1] = (_Float16)h1;
            *(int*)&hbuf[p ^ 1][n][hid0] = pk.i32;

            // prefetch next step's x-part before the barrier (independent of h)
            const int ttn = (tt + 1 < CHUNK) ? (tt + 1) : 0;  // boundary: dummy
            const f16x4 xv = *(const f16x4*)&xbuf[ttn][n][0];
            f16x8 b2 = {};
            b2[0] = xv[0]; b2[1] = xv[1]; b2[2] = xv[2];
            accxA = f32x4{biasA[0], biasA[1], biasA[2], biasA[3]};
            accxB = f32x4{biasB[0], biasB[1], biasB[2], biasB[3]};
            accxA = __builtin_amdgcn_mfma_f32_16x16x32_f16(a2A, b2, accxA, 0, 0, 0);
            accxB = __builtin_amdgcn_mfma_f32_16x16x32_f16(a2B, b2, accxB, 0, 0, 0);

            __syncthreads();
        }
    }

    // ---- epilogue: out[tb+m][cc] = b_fc[cc] + sum_k W_fc[cc][k]*h[m][k] ----
    // final h (t=512) is in hbuf[0]; last loop barrier ordered it.
    if (tid < 48) {
        const int m = tid / 3, cc = tid % 3;
        float acc = b_fc[cc];
#pragma unroll
        for (int k = 0; k < 32; ++k)
            acc = fmaf(W_fc[cc * 32 + k], (float)hbuf[0][m][k], acc);
        out[(tb + m) * 3 + cc] = acc;
    }
}

extern "C" void kernel_launch(void* const* d_in, const int* in_sizes, int n_in,
                              void* d_out, int out_size, void* d_ws, size_t ws_size,
                              hipStream_t stream) {
    const float* x    = (const float*)d_in[0];
    const float* W_ih = (const float*)d_in[1];
    const float* W_hh = (const float*)d_in[2];
    const float* b_ih = (const float*)d_in[3];
    const float* b_hh = (const float*)d_in[4];
    const float* W_fc = (const float*)d_in[5];
    const float* b_fc = (const float*)d_in[6];
    float* out = (float*)d_out;

    dim3 grid(B_TOT / 16);   // 256 blocks, one 16-batch tile each
    dim3 block(256);         // 4 waves, gate-split
    lstm_perm<<<grid, block, 0, stream>>>(x, W_ih, W_hh, b_ih, b_hh, W_fc, b_fc, out);
}

// Round 4
// 205.585 us; speedup vs baseline: 2.7534x; 1.0202x over previous
//
#include <hip/hip_runtime.h>
#include <cstdint>

// B=4096, T=512, I=3, H=32, C=3
#define B_TOT 4096
#define T_LEN 512
#define CHUNK 128
#define LOG2E 1.44269504088896340736f
#define HSTR  40   // hbuf inner stride in halves (80 B): 16B-aligned b128 frags

typedef _Float16 f16x8 __attribute__((ext_vector_type(8)));
typedef _Float16 f16x4 __attribute__((ext_vector_type(4)));
typedef float    f32x4 __attribute__((ext_vector_type(4)));

__device__ __forceinline__ float ex2(float v)  { return __builtin_amdgcn_exp2f(v); }
__device__ __forceinline__ float rcp_(float v) { return __builtin_amdgcn_rcpf(v); }

// 8-way hid split. Block = 512 thr = 8 waves, one 16-batch tile.
// Wave w owns hids [4w, 4w+4). One gate-MFMA per step:
//   D tile rows m: gate = m&3, hid = 4w + (m>>2)  (i,f,g,o = 0,1,2,3)
//   => lane (n,kq)'s 4 acc values = complete (i,f,g,o) of state (batch n, hid 4w+kq).
// exp2 scale folded into A rows: sigmoid rows * -log2e, tanh(g) rows * -2log2e.
// Bias folded into the x-MFMA via K-slot 3 (xbuf pad staged as 1.0).
__global__ __launch_bounds__(512, 2)
void lstm_w8(const float* __restrict__ x,
             const float* __restrict__ W_ih,
             const float* __restrict__ W_hh,
             const float* __restrict__ b_ih,
             const float* __restrict__ b_hh,
             const float* __restrict__ W_fc,
             const float* __restrict__ b_fc,
             float* __restrict__ out)
{
    __shared__ __align__(16) _Float16 hbuf[2][16][HSTR];   // 2.5 KB
    __shared__ __align__(16) _Float16 xbuf[CHUNK][16][4];  // 16 KB

    const int tid  = threadIdx.x;
    const int wave = tid >> 6;        // 0..7
    const int lane = tid & 63;
    const int n    = lane & 15;       // batch column
    const int kq   = lane >> 4;
    const int tb   = blockIdx.x * 16;

    // ---- A-fragment row m = n: gate (n&3), hid 4w + (n>>2) ----
    const int   gate_m = n & 3;
    const int   hid_m  = 4 * wave + (n >> 2);
    const int   Rm     = gate_m * 32 + hid_m;                 // W row (i,f,g,o blocks)
    const float sm     = (gate_m == 2) ? (-2.0f * LOG2E) : (-LOG2E);

    f16x8 aW;
#pragma unroll
    for (int j = 0; j < 8; ++j)
        aW[j] = (_Float16)(sm * W_hh[Rm * 32 + 8 * kq + j]);

    f16x8 a2 = {};                    // x-weights + bias, K-padded (kq==0 lanes)
    if (kq == 0) {
        a2[0] = (_Float16)(sm * W_ih[Rm * 3 + 0]);
        a2[1] = (_Float16)(sm * W_ih[Rm * 3 + 1]);
        a2[2] = (_Float16)(sm * W_ih[Rm * 3 + 2]);
        a2[3] = (_Float16)(sm * (b_ih[Rm] + b_hh[Rm]));      // bias via k=3 slot
    }

    // my state: (batch n, hid 4w+kq)
    const int hid_s = 4 * wave + kq;

    // zero h(0) buffers
    {
        int* hz = (int*)&hbuf[0][0][0];
        for (int i = tid; i < (2 * 16 * HSTR) / 2; i += 512) hz[i] = 0;
    }

    float c = 0.0f;
    f32x4 accx;   // prefetched x-contribution (incl. bias)

    for (int tc = 0; tc < T_LEN; tc += CHUNK) {
        // ---- stage x chunk as fp16, pad slot = 1.0 (bias trick) ----
#pragma unroll
        for (int s = 0; s < 4; ++s) {
            const int idx = tid + s * 512;          // 2048 (t,m) pairs
            const int tl = idx >> 4, m = idx & 15;
            const float* xp = x + ((size_t)(tb + m) * T_LEN + (tc + tl)) * 3;
            f16x4 v;
            v[0] = (_Float16)xp[0]; v[1] = (_Float16)xp[1];
            v[2] = (_Float16)xp[2]; v[3] = (_Float16)1.0f;
            *(f16x4*)&xbuf[tl][m][0] = v;
        }
        __syncthreads();

        {   // accx for first step of chunk
            const f16x4 xv = *(const f16x4*)&xbuf[0][n][0];
            f16x8 b2 = {};
            if (kq == 0) { b2[0] = xv[0]; b2[1] = xv[1]; b2[2] = xv[2]; b2[3] = xv[3]; }
            accx = f32x4{0.f, 0.f, 0.f, 0.f};
            accx = __builtin_amdgcn_mfma_f32_16x16x32_f16(a2, b2, accx, 0, 0, 0);
        }

#pragma unroll 2
        for (int tt = 0; tt < CHUNK; ++tt) {
            const int p = tt & 1;   // tc is a multiple of CHUNK (even)

            // post-barrier critical path: read h -> 1 MFMA -> activations -> write
            const f16x8 bh  = *(const f16x8*)&hbuf[p][n][8 * kq];
            const f32x4 acc = __builtin_amdgcn_mfma_f32_16x16x32_f16(aW, bh, accx, 0, 0, 0);

            const float iv = rcp_(1.0f + ex2(acc[0]));
            const float fv = rcp_(1.0f + ex2(acc[1]));
            const float gv = fmaf(2.0f, rcp_(1.0f + ex2(acc[2])), -1.0f);
            const float ov = rcp_(1.0f + ex2(acc[3]));

            c = fmaf(fv, c, iv * gv);
            const float th = fmaf(2.0f, rcp_(1.0f + ex2(c * (-2.0f * LOG2E))), -1.0f);
            const float h  = ov * th;

            hbuf[p ^ 1][n][hid_s] = (_Float16)h;

            // prefetch next step's x-part (independent of h) before the barrier
            const int ttn = (tt + 1 < CHUNK) ? (tt + 1) : 0;   // boundary: dummy
            const f16x4 xv = *(const f16x4*)&xbuf[ttn][n][0];
            f16x8 b2 = {};
            if (kq == 0) { b2[0] = xv[0]; b2[1] = xv[1]; b2[2] = xv[2]; b2[3] = xv[3]; }
            accx = f32x4{0.f, 0.f, 0.f, 0.f};
            accx = __builtin_amdgcn_mfma_f32_16x16x32_f16(a2, b2, accx, 0, 0, 0);

            __syncthreads();
        }
    }

    // ---- epilogue: out[tb+m][cc] = b_fc[cc] + sum_k W_fc[cc][k]*h[m][k] ----
    // final h (t=512) is in hbuf[0]; last loop barrier ordered it.
    if (tid < 48) {
        const int m = tid / 3, cc = tid % 3;
        float acc = b_fc[cc];
#pragma unroll
        for (int k = 0; k < 32; ++k)
            acc = fmaf(W_fc[cc * 32 + k], (float)hbuf[0][m][k], acc);
        out[(tb + m) * 3 + cc] = acc;
    }
}

extern "C" void kernel_launch(void* const* d_in, const int* in_sizes, int n_in,
                              void* d_out, int out_size, void* d_ws, size_t ws_size,
                              hipStream_t stream) {
    const float* x    = (const float*)d_in[0];
    const float* W_ih = (const float*)d_in[1];
    const float* W_hh = (const float*)d_in[2];
    const float* b_ih = (const float*)d_in[3];
    const float* b_hh = (const float*)d_in[4];
    const float* W_fc = (const float*)d_in[5];
    const float* b_fc = (const float*)d_in[6];
    float* out = (float*)d_out;

    dim3 grid(B_TOT / 16);   // 256 blocks, one 16-batch tile each
    dim3 block(512);         // 8 waves, 8-way hid split -> 2 waves/SIMD
    lstm_w8<<<grid, block, 0, stream>>>(x, W_ih, W_hh, b_ih, b_hh, W_fc, b_fc, out);
}

// Round 5
// 193.464 us; speedup vs baseline: 2.9259x; 1.0627x over previous
//
#include <hip/hip_runtime.h>
#include <cstdint>

// B=4096, T=512, I=3, H=32, C=3
#define B_TOT 4096
#define T_LEN 512
#define CHUNK 128
#define LOG2E 1.44269504088896340736f
#define HSTR  40   // hbuf inner stride in halves (80 B): 16B-aligned b128 frags

typedef _Float16 f16x8 __attribute__((ext_vector_type(8)));
typedef _Float16 f16x4 __attribute__((ext_vector_type(4)));
typedef float    f32x4 __attribute__((ext_vector_type(4)));

__device__ __forceinline__ float ex2(float v)  { return __builtin_amdgcn_exp2f(v); }
__device__ __forceinline__ float rcp_(float v) { return __builtin_amdgcn_rcpf(v); }

// 8-batch tile, 4 waves/block, 512 blocks -> 2 independent blocks per CU.
// Wave w owns hids [8w, 8w+8) via TWO gate-MFMAs sharing one B fragment
// (B[k][n] = h[batch n&7][hid k]; columns 8..15 duplicate batches 0..7):
//   MFMA#1 rows m: gate = m&3, hid = 8w + (m>>2)
//   MFMA#2 rows m: gate = m&3, hid = 8w + 4 + (m>>2)
// Lane (n,kq) acc quad = (i,f,g,o) of (batch n&7, hid 8w+kq [+4 if n>=8]).
// exp2 scale folded into A rows; bias folded into x-MFMA via K-slot 3 (pad=1.0).
__global__ __launch_bounds__(256, 2)
void lstm_b8(const float* __restrict__ x,
             const float* __restrict__ W_ih,
             const float* __restrict__ W_hh,
             const float* __restrict__ b_ih,
             const float* __restrict__ b_hh,
             const float* __restrict__ W_fc,
             const float* __restrict__ b_fc,
             float* __restrict__ out)
{
    __shared__ __align__(16) _Float16 hbuf[2][8][HSTR];   // 1.25 KB
    __shared__ __align__(16) _Float16 xbuf[CHUNK][8][4];  // 8 KB

    const int tid  = threadIdx.x;
    const int wave = tid >> 6;        // 0..3
    const int lane = tid & 63;
    const int n    = lane & 15;
    const int kq   = lane >> 4;
    const int nb   = n & 7;           // batch column
    const int tb   = blockIdx.x * 8;

    // ---- A-fragment rows (m = n) for the two gate-MFMAs ----
    const int   gate_m = n & 3;
    const int   hl_m   = n >> 2;                       // 0..3
    const int   R1     = gate_m * 32 + 8 * wave + hl_m;
    const int   R2     = R1 + 4;
    const float sm     = (gate_m == 2) ? (-2.0f * LOG2E) : (-LOG2E);

    f16x8 aW1, aW2;
#pragma unroll
    for (int j = 0; j < 8; ++j) {
        aW1[j] = (_Float16)(sm * W_hh[R1 * 32 + 8 * kq + j]);
        aW2[j] = (_Float16)(sm * W_hh[R2 * 32 + 8 * kq + j]);
    }
    f16x8 a21 = {}, a22 = {};         // x-weights + bias (kq==0 lanes carry K 0..3)
    if (kq == 0) {
        a21[0] = (_Float16)(sm * W_ih[R1 * 3 + 0]);
        a21[1] = (_Float16)(sm * W_ih[R1 * 3 + 1]);
        a21[2] = (_Float16)(sm * W_ih[R1 * 3 + 2]);
        a21[3] = (_Float16)(sm * (b_ih[R1] + b_hh[R1]));
        a22[0] = (_Float16)(sm * W_ih[R2 * 3 + 0]);
        a22[1] = (_Float16)(sm * W_ih[R2 * 3 + 1]);
        a22[2] = (_Float16)(sm * W_ih[R2 * 3 + 2]);
        a22[3] = (_Float16)(sm * (b_ih[R2] + b_hh[R2]));
    }

    // my state: (batch nb, hid_s)
    const int hid_s = 8 * wave + kq + ((n >> 3) ? 4 : 0);

    // zero h(0) buffer (hbuf[0] = 160 ints)
    if (tid < 160) ((int*)&hbuf[0][0][0])[tid] = 0;

    float c = 0.0f;
    f32x4 accx1, accx2;   // prefetched x-contribution (incl. bias)

    for (int tc = 0; tc < T_LEN; tc += CHUNK) {
        // ---- stage x chunk as fp16, pad slot = 1.0 (bias trick) ----
#pragma unroll
        for (int s = 0; s < 4; ++s) {
            const int idx = tid + s * 256;          // 1024 (t,m) pairs
            const int tl = idx >> 3, m = idx & 7;
            const float* xp = x + ((size_t)(tb + m) * T_LEN + (tc + tl)) * 3;
            f16x4 v;
            v[0] = (_Float16)xp[0]; v[1] = (_Float16)xp[1];
            v[2] = (_Float16)xp[2]; v[3] = (_Float16)1.0f;
            *(f16x4*)&xbuf[tl][m][0] = v;
        }
        __syncthreads();

        {   // accx for first step of chunk
            const f16x4 xv = *(const f16x4*)&xbuf[0][nb][0];
            f16x8 b2 = {};
            if (kq == 0) { b2[0] = xv[0]; b2[1] = xv[1]; b2[2] = xv[2]; b2[3] = xv[3]; }
            const f32x4 z = {0.f, 0.f, 0.f, 0.f};
            accx1 = __builtin_amdgcn_mfma_f32_16x16x32_f16(a21, b2, z, 0, 0, 0);
            accx2 = __builtin_amdgcn_mfma_f32_16x16x32_f16(a22, b2, z, 0, 0, 0);
        }

#pragma unroll 2
        for (int tt = 0; tt < CHUNK; ++tt) {
            const int p = tt & 1;   // tc is a multiple of CHUNK (even)

            // post-barrier critical path: read h -> 2 MFMA -> select -> trans -> write
            const f16x8 bh  = *(const f16x8*)&hbuf[p][nb][8 * kq];
            const f32x4 ac1 = __builtin_amdgcn_mfma_f32_16x16x32_f16(aW1, bh, accx1, 0, 0, 0);
            const f32x4 ac2 = __builtin_amdgcn_mfma_f32_16x16x32_f16(aW2, bh, accx2, 0, 0, 0);

            const bool hi = (n >> 3) != 0;
            const float a0 = hi ? ac2[0] : ac1[0];
            const float a1 = hi ? ac2[1] : ac1[1];
            const float a2 = hi ? ac2[2] : ac1[2];
            const float a3 = hi ? ac2[3] : ac1[3];

            const float iv = rcp_(1.0f + ex2(a0));
            const float fv = rcp_(1.0f + ex2(a1));
            const float gv = fmaf(2.0f, rcp_(1.0f + ex2(a2)), -1.0f);
            const float ov = rcp_(1.0f + ex2(a3));

            c = fmaf(fv, c, iv * gv);
            const float th = fmaf(2.0f, rcp_(1.0f + ex2(c * (-2.0f * LOG2E))), -1.0f);
            const float h  = ov * th;

            hbuf[p ^ 1][nb][hid_s] = (_Float16)h;

            // prefetch next step's x-part (independent of h) before the barrier
            const int ttn = (tt + 1 < CHUNK) ? (tt + 1) : 0;   // boundary: dummy
            const f16x4 xv = *(const f16x4*)&xbuf[ttn][nb][0];
            f16x8 b2 = {};
            if (kq == 0) { b2[0] = xv[0]; b2[1] = xv[1]; b2[2] = xv[2]; b2[3] = xv[3]; }
            const f32x4 z = {0.f, 0.f, 0.f, 0.f};
            accx1 = __builtin_amdgcn_mfma_f32_16x16x32_f16(a21, b2, z, 0, 0, 0);
            accx2 = __builtin_amdgcn_mfma_f32_16x16x32_f16(a22, b2, z, 0, 0, 0);

            __syncthreads();
        }
    }

    // ---- epilogue: out[tb+m][cc] = b_fc[cc] + sum_k W_fc[cc][k]*h[m][k] ----
    // final h (t=512) is in hbuf[0]; last loop barrier ordered it.
    if (tid < 24) {
        const int m = tid / 3, cc = tid % 3;
        float acc = b_fc[cc];
#pragma unroll
        for (int k = 0; k < 32; ++k)
            acc = fmaf(W_fc[cc * 32 + k], (float)hbuf[0][m][k], acc);
        out[(tb + m) * 3 + cc] = acc;
    }
}

extern "C" void kernel_launch(void* const* d_in, const int* in_sizes, int n_in,
                              void* d_out, int out_size, void* d_ws, size_t ws_size,
                              hipStream_t stream) {
    const float* x    = (const float*)d_in[0];
    const float* W_ih = (const float*)d_in[1];
    const float* W_hh = (const float*)d_in[2];
    const float* b_ih = (const float*)d_in[3];
    const float* b_hh = (const float*)d_in[4];
    const float* W_fc = (const float*)d_in[5];
    const float* b_fc = (const float*)d_in[6];
    float* out = (float*)d_out;

    dim3 grid(B_TOT / 8);    // 512 blocks -> 2 independent blocks per CU
    dim3 block(256);         // 4 waves, 8-way hid split per block
    lstm_b8<<<grid, block, 0, stream>>>(x, W_ih, W_hh, b_ih, b_hh, W_fc, b_fc, out);
}